// Round 1
// baseline (605.055 us; speedup 1.0000x reference)
//
#include <hip/hip_runtime.h>
#include <cstdint>
#include <cstddef>

#define NN 50000
#define NE 800000
#define RREL 5

static __device__ __forceinline__ float lrelu(float v) { return v > 0.f ? v : 0.01f * v; }

// ---------------------------------------------------------------------------
// Generic 64x64-tile f32 GEMM: C_tile = op(A[M,K] @ B[K,64] (+bias))
// B is a contiguous [K,64] block at B0 + blockIdx.y*bstrideB.
// EPI: 0 = store, 1 = leaky_relu store, 2 = out += leaky_relu(...)
// ---------------------------------------------------------------------------
template<int K, int EPI>
__launch_bounds__(256)
__global__ void gemm_tile(const float* __restrict__ A, int lda,
                          const float* __restrict__ B0, int bstrideB,
                          const float* __restrict__ bias, int bstride_bias,
                          float* __restrict__ C, int ldc, int M)
{
    __shared__ float As[64][68];   // transposed: As[k][row]
    __shared__ float Bs[64][64];   // Bs[k][col]
    const float* B = B0 + (size_t)blockIdx.y * bstrideB;
    const int row0 = blockIdx.x * 64;
    const int t = threadIdx.x;
    const int tx = t & 15, ty = t >> 4;

    float acc[4][4] = {};

    for (int kc = 0; kc < K; kc += 64) {
        // stage A chunk (transposed) : 64 rows x 64 k
        {
            int arow = t >> 4, akk = (t & 15) << 2;
            #pragma unroll
            for (int rp = 0; rp < 64; rp += 16) {
                int r = rp + arow, gr = row0 + r;
                float4 v = make_float4(0.f, 0.f, 0.f, 0.f);
                if (gr < M) v = *(const float4*)&A[(size_t)gr * lda + kc + akk];
                As[akk + 0][r] = v.x; As[akk + 1][r] = v.y;
                As[akk + 2][r] = v.z; As[akk + 3][r] = v.w;
            }
        }
        // stage B chunk
        #pragma unroll
        for (int idx = t; idx < 1024; idx += 256) {
            int k = idx >> 4, c4 = (idx & 15) << 2;
            *(float4*)&Bs[k][c4] = *(const float4*)&B[(size_t)(kc + k) * 64 + c4];
        }
        __syncthreads();

        #pragma unroll 8
        for (int k = 0; k < 64; ++k) {
            float4 av = *(const float4*)&As[k][ty * 4];
            float4 bv = *(const float4*)&Bs[k][tx * 4];
            float ar[4] = {av.x, av.y, av.z, av.w};
            float br[4] = {bv.x, bv.y, bv.z, bv.w};
            #pragma unroll
            for (int i = 0; i < 4; ++i)
                #pragma unroll
                for (int j = 0; j < 4; ++j)
                    acc[i][j] = fmaf(ar[i], br[j], acc[i][j]);
        }
        __syncthreads();
    }

    float bb[4] = {0.f, 0.f, 0.f, 0.f};
    if (bias) {
        const float* bp = bias + (size_t)blockIdx.y * bstride_bias + tx * 4;
        bb[0] = bp[0]; bb[1] = bp[1]; bb[2] = bp[2]; bb[3] = bp[3];
    }
    const int ccol = blockIdx.y * 64 + tx * 4;
    #pragma unroll
    for (int i = 0; i < 4; ++i) {
        int gr = row0 + ty * 4 + i;
        if (gr >= M) continue;
        float v[4];
        #pragma unroll
        for (int j = 0; j < 4; ++j) {
            v[j] = acc[i][j] + bb[j];
            if (EPI >= 1) v[j] = lrelu(v[j]);
        }
        float* p = &C[(size_t)gr * ldc + ccol];
        if (EPI == 2) {
            float4 o = *(const float4*)p;
            v[0] += o.x; v[1] += o.y; v[2] += o.z; v[3] += o.w;
        }
        *(float4*)p = make_float4(v[0], v[1], v[2], v[3]);
    }
}

// ---------------------------------------------------------------------------
// e_init[n][:] = sum_r S[n,r] * (e_prev[n] @ Wbot[r] + b[r])
// relW is [R,128,64]; Wbot[r] = rows 64..127 => offset r*8192 + 4096.
// ---------------------------------------------------------------------------
__launch_bounds__(256)
__global__ void einit_kernel(const float* __restrict__ Ain,
                             const float* __restrict__ relW,
                             const float* __restrict__ relb,
                             const float* __restrict__ S,
                             float* __restrict__ Eout, int M)
{
    __shared__ float As[64][68];
    __shared__ float Bs[64][64];
    const int row0 = blockIdx.x * 64;
    const int t = threadIdx.x;
    const int tx = t & 15, ty = t >> 4;

    // stage A (transposed)
    {
        int arow = t >> 4, akk = (t & 15) << 2;
        #pragma unroll
        for (int rp = 0; rp < 64; rp += 16) {
            int r = rp + arow, gr = row0 + r;
            float4 v = make_float4(0.f, 0.f, 0.f, 0.f);
            if (gr < M) v = *(const float4*)&Ain[(size_t)gr * 64 + akk];
            As[akk + 0][r] = v.x; As[akk + 1][r] = v.y;
            As[akk + 2][r] = v.z; As[akk + 3][r] = v.w;
        }
    }
    // stage Wbot[0]
    #pragma unroll
    for (int idx = t; idx < 1024; idx += 256) {
        int k = idx >> 4, c4 = (idx & 15) << 2;
        *(float4*)&Bs[k][c4] = *(const float4*)&relW[4096 + k * 64 + c4];
    }

    // prefetch S for this thread's 4 rows
    float sv[4][RREL];
    #pragma unroll
    for (int i = 0; i < 4; ++i) {
        int gr = row0 + ty * 4 + i;
        #pragma unroll
        for (int r = 0; r < RREL; ++r)
            sv[i][r] = (gr < M) ? S[(size_t)gr * RREL + r] : 0.f;
    }

    float accF[4][4] = {};
    __syncthreads();

    for (int r = 0; r < RREL; ++r) {
        float tmp[4][4] = {};
        #pragma unroll 8
        for (int k = 0; k < 64; ++k) {
            float4 av = *(const float4*)&As[k][ty * 4];
            float4 bv = *(const float4*)&Bs[k][tx * 4];
            float ar[4] = {av.x, av.y, av.z, av.w};
            float br[4] = {bv.x, bv.y, bv.z, bv.w};
            #pragma unroll
            for (int i = 0; i < 4; ++i)
                #pragma unroll
                for (int j = 0; j < 4; ++j)
                    tmp[i][j] = fmaf(ar[i], br[j], tmp[i][j]);
        }
        float bb[4];
        const float* bp = relb + r * 64 + tx * 4;
        bb[0] = bp[0]; bb[1] = bp[1]; bb[2] = bp[2]; bb[3] = bp[3];
        #pragma unroll
        for (int i = 0; i < 4; ++i)
            #pragma unroll
            for (int j = 0; j < 4; ++j)
                accF[i][j] = fmaf(sv[i][r], tmp[i][j] + bb[j], accF[i][j]);

        __syncthreads();
        if (r + 1 < RREL) {
            #pragma unroll
            for (int idx = t; idx < 1024; idx += 256) {
                int k = idx >> 4, c4 = (idx & 15) << 2;
                *(float4*)&Bs[k][c4] =
                    *(const float4*)&relW[(size_t)(r + 1) * 8192 + 4096 + k * 64 + c4];
            }
            __syncthreads();
        }
    }

    #pragma unroll
    for (int i = 0; i < 4; ++i) {
        int gr = row0 + ty * 4 + i;
        if (gr >= M) continue;
        *(float4*)&Eout[(size_t)gr * 64 + tx * 4] =
            make_float4(accF[i][0], accF[i][1], accF[i][2], accF[i][3]);
    }
}

// ---------------------------------------------------------------------------
// per-edge weight w_e = lambda * exp(-edge_time . beta); S[dst,r] += w_e
// ---------------------------------------------------------------------------
__launch_bounds__(256)
__global__ void edge_w_kernel(const float* __restrict__ etime,
                              const float* __restrict__ beta,
                              const int* __restrict__ dst,
                              const int* __restrict__ etype,
                              const float* __restrict__ lambda_p,
                              float* __restrict__ w, float* __restrict__ S)
{
    int e = blockIdx.x * 256 + threadIdx.x;
    if (e >= NE) return;
    float b[12];
    #pragma unroll
    for (int j = 0; j < 12; ++j) b[j] = beta[j];
    const float* et = etime + (size_t)e * 12;
    float4 v0 = *(const float4*)(et);
    float4 v1 = *(const float4*)(et + 4);
    float4 v2 = *(const float4*)(et + 8);
    float logit = v0.x*b[0] + v0.y*b[1] + v0.z*b[2] + v0.w*b[3]
                + v1.x*b[4] + v1.y*b[5] + v1.z*b[6] + v1.w*b[7]
                + v2.x*b[8] + v2.y*b[9] + v2.z*b[10] + v2.w*b[11];
    float we = lambda_p[0] * expf(-logit);
    w[e] = we;
    atomicAdd(&S[(size_t)dst[e] * RREL + etype[e]], we);
}

// ---------------------------------------------------------------------------
// out[dst][lane] += w_e * ytop[src, r*64 + lane]   (one wave per edge)
// ---------------------------------------------------------------------------
__launch_bounds__(256)
__global__ void edge_scatter(const int* __restrict__ src,
                             const int* __restrict__ dst,
                             const int* __restrict__ etype,
                             const float* __restrict__ w,
                             const float* __restrict__ yt,
                             float* __restrict__ out)
{
    int wid = (blockIdx.x * 256 + threadIdx.x) >> 6;
    int lane = threadIdx.x & 63;
    int nw = (gridDim.x * 256) >> 6;
    for (int e = wid; e < NE; e += nw) {
        int s = src[e], d = dst[e], r = etype[e];
        float we = w[e];
        float v = we * yt[(size_t)s * 320 + (r << 6) + lane];
        atomicAdd(&out[((size_t)d << 6) + lane], v);
    }
}

// ---------------------------------------------------------------------------
extern "C" void kernel_launch(void* const* d_in, const int* in_sizes, int n_in,
                              void* d_out, int out_size, void* d_ws, size_t ws_size,
                              hipStream_t stream)
{
    const float* x        = (const float*)d_in[0];
    const int*   eidx     = (const int*)d_in[1];
    const int*   etype    = (const int*)d_in[2];
    const float* etime    = (const float*)d_in[3];
    const float* lambda_p = (const float*)d_in[4];
    const float* beta     = (const float*)d_in[5];
    const float* field_W  = (const float*)d_in[6];
    const float* field_b  = (const float*)d_in[7];
    const float* rel1_W   = (const float*)d_in[8];
    const float* rel1_b   = (const float*)d_in[9];
    const float* rel2_W   = (const float*)d_in[10];
    const float* rel2_b   = (const float*)d_in[11];
    const float* out0_W   = (const float*)d_in[12];
    const float* out0_b   = (const float*)d_in[13];
    const float* out1_W   = (const float*)d_in[14];
    const float* out1_b   = (const float*)d_in[15];
    const float* out2_W   = (const float*)d_in[16];
    const float* out2_b   = (const float*)d_in[17];
    const int* src = eidx;
    const int* dst = eidx + NE;
    float* out = (float*)d_out;

    // workspace carve-up (all 256B aligned)
    char* wsb = (char*)d_ws;
    size_t off = 0;
    auto carve = [&](size_t bytes) -> float* {
        float* p = (float*)(wsb + off);
        off += (bytes + 255) & ~(size_t)255;
        return p;
    };
    float* w_e = carve((size_t)NE * 4);            // 3.2 MB
    float* S   = carve((size_t)NN * RREL * 4);     // 1.0 MB
    float* e0  = carve((size_t)NN * 64 * 4);       // 12.8 MB
    float* e1  = carve((size_t)NN * 64 * 4);       // 12.8 MB
    float* e2  = carve((size_t)NN * 64 * 4);       // 12.8 MB
    float* yt  = carve((size_t)NN * 320 * 4);      // 64 MB (reused layer 2)

    const int NT = (NN + 63) / 64;                 // 782 row tiles
    dim3 blk(256);
    dim3 g1(NT, 1), g5(NT, RREL);

    // 1) edge weights + per-(dst,r) scalar sums (layer-independent)
    hipMemsetAsync(S, 0, (size_t)NN * RREL * 4, stream);
    edge_w_kernel<<<(NE + 255) / 256, blk, 0, stream>>>(etime, beta, dst, etype,
                                                        lambda_p, w_e, S);

    // 2) e0 = x @ field_W + field_b
    gemm_tile<128, 0><<<g1, blk, 0, stream>>>(x, 128, field_W, 0, field_b, 0,
                                              e0, 64, NN);

    // ---- layer 1 ----
    gemm_tile<64, 0><<<g5, blk, 0, stream>>>(e0, 64, rel1_W, 8192, nullptr, 0,
                                             yt, 320, NN);          // ytop1
    einit_kernel<<<g1, blk, 0, stream>>>(e0, rel1_W, rel1_b, S, e1, NN);
    edge_scatter<<<2048, blk, 0, stream>>>(src, dst, etype, w_e, yt, e1);

    // ---- layer 2 ----
    gemm_tile<64, 0><<<g5, blk, 0, stream>>>(e1, 64, rel2_W, 8192, nullptr, 0,
                                             yt, 320, NN);          // ytop2
    einit_kernel<<<g1, blk, 0, stream>>>(e1, rel2_W, rel2_b, S, e2, NN);
    edge_scatter<<<2048, blk, 0, stream>>>(src, dst, etype, w_e, yt, e2);

    // ---- output head: out = lr(e2@W2+b2) + lr(e1@W1+b1) + lr(e0@W0+b0) ----
    gemm_tile<64, 1><<<g1, blk, 0, stream>>>(e2, 64, out2_W, 0, out2_b, 0,
                                             out, 64, NN);
    gemm_tile<64, 2><<<g1, blk, 0, stream>>>(e1, 64, out1_W, 0, out1_b, 0,
                                             out, 64, NN);
    gemm_tile<64, 2><<<g1, blk, 0, stream>>>(e0, 64, out0_W, 0, out0_b, 0,
                                             out, 64, NN);
}

// Round 2
// 443.898 us; speedup vs baseline: 1.3630x; 1.3630x over previous
//
#include <hip/hip_runtime.h>
#include <cstdint>
#include <cstddef>

#define NN 50000
#define NE 800000
#define RREL 5
#define SCAN_NB 196   // ceil(NN/256)

static __device__ __forceinline__ float lrelu(float v) { return v > 0.f ? v : 0.01f * v; }

// ---------------------------------------------------------------------------
// Generic 64x64-tile f32 GEMM: C_tile = op(A[M,K] @ B[K,64] (+bias))
// EPI: 0 = store, 1 = leaky_relu store, 2 = out += leaky_relu(...)
// ---------------------------------------------------------------------------
template<int K, int EPI>
__launch_bounds__(256)
__global__ void gemm_tile(const float* __restrict__ A, int lda,
                          const float* __restrict__ B0, int bstrideB,
                          const float* __restrict__ bias, int bstride_bias,
                          float* __restrict__ C, int ldc, int M)
{
    __shared__ float As[64][68];   // transposed: As[k][row]
    __shared__ float Bs[64][64];   // Bs[k][col]
    const float* B = B0 + (size_t)blockIdx.y * bstrideB;
    const int row0 = blockIdx.x * 64;
    const int t = threadIdx.x;
    const int tx = t & 15, ty = t >> 4;

    float acc[4][4] = {};

    for (int kc = 0; kc < K; kc += 64) {
        {
            int arow = t >> 4, akk = (t & 15) << 2;
            #pragma unroll
            for (int rp = 0; rp < 64; rp += 16) {
                int r = rp + arow, gr = row0 + r;
                float4 v = make_float4(0.f, 0.f, 0.f, 0.f);
                if (gr < M) v = *(const float4*)&A[(size_t)gr * lda + kc + akk];
                As[akk + 0][r] = v.x; As[akk + 1][r] = v.y;
                As[akk + 2][r] = v.z; As[akk + 3][r] = v.w;
            }
        }
        #pragma unroll
        for (int idx = t; idx < 1024; idx += 256) {
            int k = idx >> 4, c4 = (idx & 15) << 2;
            *(float4*)&Bs[k][c4] = *(const float4*)&B[(size_t)(kc + k) * 64 + c4];
        }
        __syncthreads();

        #pragma unroll 8
        for (int k = 0; k < 64; ++k) {
            float4 av = *(const float4*)&As[k][ty * 4];
            float4 bv = *(const float4*)&Bs[k][tx * 4];
            float ar[4] = {av.x, av.y, av.z, av.w};
            float br[4] = {bv.x, bv.y, bv.z, bv.w};
            #pragma unroll
            for (int i = 0; i < 4; ++i)
                #pragma unroll
                for (int j = 0; j < 4; ++j)
                    acc[i][j] = fmaf(ar[i], br[j], acc[i][j]);
        }
        __syncthreads();
    }

    float bb[4] = {0.f, 0.f, 0.f, 0.f};
    if (bias) {
        const float* bp = bias + (size_t)blockIdx.y * bstride_bias + tx * 4;
        bb[0] = bp[0]; bb[1] = bp[1]; bb[2] = bp[2]; bb[3] = bp[3];
    }
    const int ccol = blockIdx.y * 64 + tx * 4;
    #pragma unroll
    for (int i = 0; i < 4; ++i) {
        int gr = row0 + ty * 4 + i;
        if (gr >= M) continue;
        float v[4];
        #pragma unroll
        for (int j = 0; j < 4; ++j) {
            v[j] = acc[i][j] + bb[j];
            if (EPI >= 1) v[j] = lrelu(v[j]);
        }
        float* p = &C[(size_t)gr * ldc + ccol];
        if (EPI == 2) {
            float4 o = *(const float4*)p;
            v[0] += o.x; v[1] += o.y; v[2] += o.z; v[3] += o.w;
        }
        *(float4*)p = make_float4(v[0], v[1], v[2], v[3]);
    }
}

// ---------------------------------------------------------------------------
// e_init[n][:] = sum_r S[n,r] * (e_prev[n] @ Wbot[r] + b[r])
// ---------------------------------------------------------------------------
__launch_bounds__(256)
__global__ void einit_kernel(const float* __restrict__ Ain,
                             const float* __restrict__ relW,
                             const float* __restrict__ relb,
                             const float* __restrict__ S,
                             float* __restrict__ Eout, int M)
{
    __shared__ float As[64][68];
    __shared__ float Bs[64][64];
    const int row0 = blockIdx.x * 64;
    const int t = threadIdx.x;
    const int tx = t & 15, ty = t >> 4;

    {
        int arow = t >> 4, akk = (t & 15) << 2;
        #pragma unroll
        for (int rp = 0; rp < 64; rp += 16) {
            int r = rp + arow, gr = row0 + r;
            float4 v = make_float4(0.f, 0.f, 0.f, 0.f);
            if (gr < M) v = *(const float4*)&Ain[(size_t)gr * 64 + akk];
            As[akk + 0][r] = v.x; As[akk + 1][r] = v.y;
            As[akk + 2][r] = v.z; As[akk + 3][r] = v.w;
        }
    }
    #pragma unroll
    for (int idx = t; idx < 1024; idx += 256) {
        int k = idx >> 4, c4 = (idx & 15) << 2;
        *(float4*)&Bs[k][c4] = *(const float4*)&relW[4096 + k * 64 + c4];
    }

    float sv[4][RREL];
    #pragma unroll
    for (int i = 0; i < 4; ++i) {
        int gr = row0 + ty * 4 + i;
        #pragma unroll
        for (int r = 0; r < RREL; ++r)
            sv[i][r] = (gr < M) ? S[(size_t)gr * RREL + r] : 0.f;
    }

    float accF[4][4] = {};
    __syncthreads();

    for (int r = 0; r < RREL; ++r) {
        float tmp[4][4] = {};
        #pragma unroll 8
        for (int k = 0; k < 64; ++k) {
            float4 av = *(const float4*)&As[k][ty * 4];
            float4 bv = *(const float4*)&Bs[k][tx * 4];
            float ar[4] = {av.x, av.y, av.z, av.w};
            float br[4] = {bv.x, bv.y, bv.z, bv.w};
            #pragma unroll
            for (int i = 0; i < 4; ++i)
                #pragma unroll
                for (int j = 0; j < 4; ++j)
                    tmp[i][j] = fmaf(ar[i], br[j], tmp[i][j]);
        }
        float bb[4];
        const float* bp = relb + r * 64 + tx * 4;
        bb[0] = bp[0]; bb[1] = bp[1]; bb[2] = bp[2]; bb[3] = bp[3];
        #pragma unroll
        for (int i = 0; i < 4; ++i)
            #pragma unroll
            for (int j = 0; j < 4; ++j)
                accF[i][j] = fmaf(sv[i][r], tmp[i][j] + bb[j], accF[i][j]);

        __syncthreads();
        if (r + 1 < RREL) {
            #pragma unroll
            for (int idx = t; idx < 1024; idx += 256) {
                int k = idx >> 4, c4 = (idx & 15) << 2;
                *(float4*)&Bs[k][c4] =
                    *(const float4*)&relW[(size_t)(r + 1) * 8192 + 4096 + k * 64 + c4];
            }
            __syncthreads();
        }
    }

    #pragma unroll
    for (int i = 0; i < 4; ++i) {
        int gr = row0 + ty * 4 + i;
        if (gr >= M) continue;
        *(float4*)&Eout[(size_t)gr * 64 + tx * 4] =
            make_float4(accF[i][0], accF[i][1], accF[i][2], accF[i][3]);
    }
}

// ---------------------------------------------------------------------------
// CSR build: histogram -> scan -> fill (dst-sorted edge list, layer-shared)
// ---------------------------------------------------------------------------
__launch_bounds__(256)
__global__ void deg_hist(const int* __restrict__ dst, int* __restrict__ deg)
{
    int e = blockIdx.x * 256 + threadIdx.x;
    if (e < NE) atomicAdd(&deg[dst[e]], 1);
}

__launch_bounds__(256)
__global__ void scan_block_sums(const int* __restrict__ deg, int* __restrict__ bsum)
{
    __shared__ int sh[256];
    int i = blockIdx.x * 256 + threadIdx.x;
    sh[threadIdx.x] = (i < NN) ? deg[i] : 0;
    __syncthreads();
    for (int s = 128; s > 0; s >>= 1) {
        if (threadIdx.x < s) sh[threadIdx.x] += sh[threadIdx.x + s];
        __syncthreads();
    }
    if (threadIdx.x == 0) bsum[blockIdx.x] = sh[0];
}

__launch_bounds__(256)
__global__ void scan_partials(int* __restrict__ bsum, int nb)
{
    __shared__ int sh[256];
    int t = threadIdx.x;
    int v = (t < nb) ? bsum[t] : 0;
    sh[t] = v; __syncthreads();
    for (int off = 1; off < 256; off <<= 1) {
        int x = (t >= off) ? sh[t - off] : 0;
        __syncthreads();
        sh[t] += x;
        __syncthreads();
    }
    if (t < nb) bsum[t] = sh[t] - v;   // exclusive
}

__launch_bounds__(256)
__global__ void scan_final(const int* __restrict__ deg, const int* __restrict__ bsum,
                           int* __restrict__ offs)
{
    __shared__ int sh[256];
    int t = threadIdx.x;
    int i = blockIdx.x * 256 + t;
    int v = (i < NN) ? deg[i] : 0;
    sh[t] = v; __syncthreads();
    for (int off = 1; off < 256; off <<= 1) {
        int x = (t >= off) ? sh[t - off] : 0;
        __syncthreads();
        sh[t] += x;
        __syncthreads();
    }
    int excl = sh[t] - v + bsum[blockIdx.x];
    if (i <= NN) offs[i] = excl;
}

// fill: per-edge weight w = lambda*exp(-etime.beta); S[dst,r] += w;
// place (src,r,w) at CSR slot of dst.
__launch_bounds__(256)
__global__ void fill_csr(const int* __restrict__ src, const int* __restrict__ dst,
                         const int* __restrict__ etype, const float* __restrict__ etime,
                         const float* __restrict__ beta, const float* __restrict__ lambda_p,
                         const int* __restrict__ offs, int* __restrict__ cursor,
                         float* __restrict__ S, uint2* __restrict__ epack)
{
    int e = blockIdx.x * 256 + threadIdx.x;
    if (e >= NE) return;
    float b[12];
    #pragma unroll
    for (int j = 0; j < 12; ++j) b[j] = beta[j];
    const float* et = etime + (size_t)e * 12;
    float4 v0 = *(const float4*)(et);
    float4 v1 = *(const float4*)(et + 4);
    float4 v2 = *(const float4*)(et + 8);
    float logit = v0.x*b[0] + v0.y*b[1] + v0.z*b[2] + v0.w*b[3]
                + v1.x*b[4] + v1.y*b[5] + v1.z*b[6] + v1.w*b[7]
                + v2.x*b[8] + v2.y*b[9] + v2.z*b[10] + v2.w*b[11];
    float we = lambda_p[0] * expf(-logit);
    int d = dst[e], r = etype[e];
    atomicAdd(&S[(size_t)d * RREL + r], we);
    int p = offs[d] + atomicAdd(&cursor[d], 1);
    epack[p] = make_uint2(((unsigned)r << 16) | (unsigned)src[e], __float_as_uint(we));
}

// ---------------------------------------------------------------------------
// gather: one wave per dst node; out[n][lane] = einit[n][lane] + sum_e w*yt[src,r,lane]
// ---------------------------------------------------------------------------
__launch_bounds__(256)
__global__ void gather_nodes(const int* __restrict__ offs, const uint2* __restrict__ epack,
                             const float* __restrict__ yt, float* __restrict__ out)
{
    int wid = (blockIdx.x * 256 + threadIdx.x) >> 6;
    int lane = threadIdx.x & 63;
    if (wid >= NN) return;
    int s0 = offs[wid], s1 = offs[wid + 1];
    size_t orow = ((size_t)wid << 6) + lane;
    float acc = out[orow];          // einit value
    float acc2 = 0.f;
    int p = s0;
    for (; p + 2 <= s1; p += 2) {
        uint2 a = epack[p];
        uint2 bq = epack[p + 1];
        float va = yt[(size_t)(a.x & 0xFFFFu) * 320 + ((a.x >> 16) << 6) + lane];
        float vb = yt[(size_t)(bq.x & 0xFFFFu) * 320 + ((bq.x >> 16) << 6) + lane];
        acc  = fmaf(__uint_as_float(a.y),  va, acc);
        acc2 = fmaf(__uint_as_float(bq.y), vb, acc2);
    }
    if (p < s1) {
        uint2 a = epack[p];
        acc = fmaf(__uint_as_float(a.y),
                   yt[(size_t)(a.x & 0xFFFFu) * 320 + ((a.x >> 16) << 6) + lane], acc);
    }
    out[orow] = acc + acc2;
}

// ---------------------------------------------------------------------------
extern "C" void kernel_launch(void* const* d_in, const int* in_sizes, int n_in,
                              void* d_out, int out_size, void* d_ws, size_t ws_size,
                              hipStream_t stream)
{
    const float* x        = (const float*)d_in[0];
    const int*   eidx     = (const int*)d_in[1];
    const int*   etype    = (const int*)d_in[2];
    const float* etime    = (const float*)d_in[3];
    const float* lambda_p = (const float*)d_in[4];
    const float* beta     = (const float*)d_in[5];
    const float* field_W  = (const float*)d_in[6];
    const float* field_b  = (const float*)d_in[7];
    const float* rel1_W   = (const float*)d_in[8];
    const float* rel1_b   = (const float*)d_in[9];
    const float* rel2_W   = (const float*)d_in[10];
    const float* rel2_b   = (const float*)d_in[11];
    const float* out0_W   = (const float*)d_in[12];
    const float* out0_b   = (const float*)d_in[13];
    const float* out1_W   = (const float*)d_in[14];
    const float* out1_b   = (const float*)d_in[15];
    const float* out2_W   = (const float*)d_in[16];
    const float* out2_b   = (const float*)d_in[17];
    const int* src = eidx;
    const int* dst = eidx + NE;
    float* out = (float*)d_out;

    char* wsb = (char*)d_ws;
    size_t off = 0;
    auto carve = [&](size_t bytes) -> void* {
        void* p = (void*)(wsb + off);
        off += (bytes + 255) & ~(size_t)255;
        return p;
    };
    int*   deg    = (int*)carve((size_t)NN * 4);            // 200 KB
    int*   offs   = (int*)carve((size_t)(NN + 1) * 4);      // 200 KB
    int*   cursor = (int*)carve((size_t)NN * 4);            // 200 KB
    int*   bsum   = (int*)carve((size_t)SCAN_NB * 4);
    float* S      = (float*)carve((size_t)NN * RREL * 4);   // 1 MB
    uint2* epack  = (uint2*)carve((size_t)NE * 8);          // 6.4 MB
    float* e0     = (float*)carve((size_t)NN * 64 * 4);     // 12.8 MB
    float* e1     = (float*)carve((size_t)NN * 64 * 4);     // 12.8 MB
    float* e2     = (float*)carve((size_t)NN * 64 * 4);     // 12.8 MB
    float* yt     = (float*)carve((size_t)NN * 320 * 4);    // 64 MB

    const int NT = (NN + 63) / 64;
    dim3 blk(256);
    dim3 g1(NT, 1), g5(NT, RREL);
    const int EB = (NE + 255) / 256;
    const int GB = (NN * 64 + 255) / 256;   // gather blocks (wave per node)

    // ---- CSR build (layer-shared) ----
    hipMemsetAsync(deg, 0, (size_t)NN * 4, stream);
    hipMemsetAsync(cursor, 0, (size_t)NN * 4, stream);
    hipMemsetAsync(S, 0, (size_t)NN * RREL * 4, stream);
    deg_hist<<<EB, blk, 0, stream>>>(dst, deg);
    scan_block_sums<<<SCAN_NB, blk, 0, stream>>>(deg, bsum);
    scan_partials<<<1, blk, 0, stream>>>(bsum, SCAN_NB);
    scan_final<<<SCAN_NB, blk, 0, stream>>>(deg, bsum, offs);
    fill_csr<<<EB, blk, 0, stream>>>(src, dst, etype, etime, beta, lambda_p,
                                     offs, cursor, S, epack);

    // ---- e0 = x @ field_W + field_b ----
    gemm_tile<128, 0><<<g1, blk, 0, stream>>>(x, 128, field_W, 0, field_b, 0,
                                              e0, 64, NN);

    // ---- layer 1 ----
    gemm_tile<64, 0><<<g5, blk, 0, stream>>>(e0, 64, rel1_W, 8192, nullptr, 0,
                                             yt, 320, NN);
    einit_kernel<<<g1, blk, 0, stream>>>(e0, rel1_W, rel1_b, S, e1, NN);
    gather_nodes<<<GB, blk, 0, stream>>>(offs, epack, yt, e1);

    // ---- layer 2 ----
    gemm_tile<64, 0><<<g5, blk, 0, stream>>>(e1, 64, rel2_W, 8192, nullptr, 0,
                                             yt, 320, NN);
    einit_kernel<<<g1, blk, 0, stream>>>(e1, rel2_W, rel2_b, S, e2, NN);
    gather_nodes<<<GB, blk, 0, stream>>>(offs, epack, yt, e2);

    // ---- output head ----
    gemm_tile<64, 1><<<g1, blk, 0, stream>>>(e2, 64, out2_W, 0, out2_b, 0,
                                             out, 64, NN);
    gemm_tile<64, 2><<<g1, blk, 0, stream>>>(e1, 64, out1_W, 0, out1_b, 0,
                                             out, 64, NN);
    gemm_tile<64, 2><<<g1, blk, 0, stream>>>(e0, 64, out0_W, 0, out0_b, 0,
                                             out, 64, NN);
}

// Round 3
// 416.931 us; speedup vs baseline: 1.4512x; 1.0647x over previous
//
#include <hip/hip_runtime.h>
#include <cstdint>
#include <cstddef>

#define NN 50000
#define NE 800000
#define RREL 5
#define SCAN_NB 196   // ceil(NN/256)

static __device__ __forceinline__ float lrelu(float v) { return v > 0.f ? v : 0.01f * v; }

// ---------------------------------------------------------------------------
// 64x64-tile f32 GEMM (used only for e0 = x @ field_W + field_b, K=128)
// ---------------------------------------------------------------------------
template<int K>
__launch_bounds__(256)
__global__ void gemm_tile(const float* __restrict__ A, int lda,
                          const float* __restrict__ B0,
                          const float* __restrict__ bias,
                          float* __restrict__ C, int M)
{
    __shared__ float As[64][68];   // transposed: As[k][row]
    __shared__ float Bs[64][64];   // Bs[k][col]
    const int row0 = blockIdx.x * 64;
    const int t = threadIdx.x;
    const int tx = t & 15, ty = t >> 4;

    float acc[4][4] = {};

    for (int kc = 0; kc < K; kc += 64) {
        {
            int arow = t >> 4, akk = (t & 15) << 2;
            #pragma unroll
            for (int rp = 0; rp < 64; rp += 16) {
                int r = rp + arow, gr = row0 + r;
                float4 v = make_float4(0.f, 0.f, 0.f, 0.f);
                if (gr < M) v = *(const float4*)&A[(size_t)gr * lda + kc + akk];
                As[akk + 0][r] = v.x; As[akk + 1][r] = v.y;
                As[akk + 2][r] = v.z; As[akk + 3][r] = v.w;
            }
        }
        #pragma unroll
        for (int idx = t; idx < 1024; idx += 256) {
            int k = idx >> 4, c4 = (idx & 15) << 2;
            *(float4*)&Bs[k][c4] = *(const float4*)&B0[(size_t)(kc + k) * 64 + c4];
        }
        __syncthreads();

        #pragma unroll 8
        for (int k = 0; k < 64; ++k) {
            float4 av = *(const float4*)&As[k][ty * 4];
            float4 bv = *(const float4*)&Bs[k][tx * 4];
            float ar[4] = {av.x, av.y, av.z, av.w};
            float br[4] = {bv.x, bv.y, bv.z, bv.w};
            #pragma unroll
            for (int i = 0; i < 4; ++i)
                #pragma unroll
                for (int j = 0; j < 4; ++j)
                    acc[i][j] = fmaf(ar[i], br[j], acc[i][j]);
        }
        __syncthreads();
    }

    float bb[4];
    {
        const float* bp = bias + tx * 4;
        bb[0] = bp[0]; bb[1] = bp[1]; bb[2] = bp[2]; bb[3] = bp[3];
    }
    #pragma unroll
    for (int i = 0; i < 4; ++i) {
        int gr = row0 + ty * 4 + i;
        if (gr >= M) continue;
        *(float4*)&C[(size_t)gr * 64 + tx * 4] =
            make_float4(acc[i][0] + bb[0], acc[i][1] + bb[1],
                        acc[i][2] + bb[2], acc[i][3] + bb[3]);
    }
}

// ---------------------------------------------------------------------------
// Fused relation kernel: per 64-row tile of A=e_prev,
//   for r in 0..R: yt[:, r*64:] = A @ Wtop[r]          (written out)
//                  accF += S[:,r] * (A @ Wbot[r] + b[r])
//   Eout = accF
// relW is [R,128,64]: Wtop[r] at r*8192, Wbot[r] at r*8192+4096.
// ---------------------------------------------------------------------------
__launch_bounds__(256)
__global__ void rel_fused(const float* __restrict__ Ain,
                          const float* __restrict__ relW,
                          const float* __restrict__ relb,
                          const float* __restrict__ S,
                          float* __restrict__ yt,
                          float* __restrict__ Eout, int M)
{
    __shared__ float As[64][68];
    __shared__ float Bs[64][64];
    const int row0 = blockIdx.x * 64;
    const int t = threadIdx.x;
    const int tx = t & 15, ty = t >> 4;

    // stage A (transposed)
    {
        int arow = t >> 4, akk = (t & 15) << 2;
        #pragma unroll
        for (int rp = 0; rp < 64; rp += 16) {
            int r = rp + arow, gr = row0 + r;
            float4 v = make_float4(0.f, 0.f, 0.f, 0.f);
            if (gr < M) v = *(const float4*)&Ain[(size_t)gr * 64 + akk];
            As[akk + 0][r] = v.x; As[akk + 1][r] = v.y;
            As[akk + 2][r] = v.z; As[akk + 3][r] = v.w;
        }
    }

    float sv[4][RREL];
    #pragma unroll
    for (int i = 0; i < 4; ++i) {
        int gr = row0 + ty * 4 + i;
        #pragma unroll
        for (int r = 0; r < RREL; ++r)
            sv[i][r] = (gr < M) ? S[(size_t)gr * RREL + r] : 0.f;
    }

    float accF[4][4] = {};

    for (int r = 0; r < RREL; ++r) {
        // ---- Wtop[r] ----
        __syncthreads();   // protect Bs (and As on first iter)
        #pragma unroll
        for (int idx = t; idx < 1024; idx += 256) {
            int k = idx >> 4, c4 = (idx & 15) << 2;
            *(float4*)&Bs[k][c4] = *(const float4*)&relW[(size_t)r * 8192 + k * 64 + c4];
        }
        __syncthreads();

        float tmp[4][4] = {};
        #pragma unroll 8
        for (int k = 0; k < 64; ++k) {
            float4 av = *(const float4*)&As[k][ty * 4];
            float4 bv = *(const float4*)&Bs[k][tx * 4];
            float ar[4] = {av.x, av.y, av.z, av.w};
            float br[4] = {bv.x, bv.y, bv.z, bv.w};
            #pragma unroll
            for (int i = 0; i < 4; ++i)
                #pragma unroll
                for (int j = 0; j < 4; ++j)
                    tmp[i][j] = fmaf(ar[i], br[j], tmp[i][j]);
        }
        #pragma unroll
        for (int i = 0; i < 4; ++i) {
            int gr = row0 + ty * 4 + i;
            if (gr < M)
                *(float4*)&yt[(size_t)gr * 320 + (r << 6) + tx * 4] =
                    make_float4(tmp[i][0], tmp[i][1], tmp[i][2], tmp[i][3]);
        }

        // ---- Wbot[r] ----
        __syncthreads();
        #pragma unroll
        for (int idx = t; idx < 1024; idx += 256) {
            int k = idx >> 4, c4 = (idx & 15) << 2;
            *(float4*)&Bs[k][c4] =
                *(const float4*)&relW[(size_t)r * 8192 + 4096 + k * 64 + c4];
        }
        __syncthreads();

        float tmp2[4][4] = {};
        #pragma unroll 8
        for (int k = 0; k < 64; ++k) {
            float4 av = *(const float4*)&As[k][ty * 4];
            float4 bv = *(const float4*)&Bs[k][tx * 4];
            float ar[4] = {av.x, av.y, av.z, av.w};
            float br[4] = {bv.x, bv.y, bv.z, bv.w};
            #pragma unroll
            for (int i = 0; i < 4; ++i)
                #pragma unroll
                for (int j = 0; j < 4; ++j)
                    tmp2[i][j] = fmaf(ar[i], br[j], tmp2[i][j]);
        }
        float bb[4];
        {
            const float* bp = relb + r * 64 + tx * 4;
            bb[0] = bp[0]; bb[1] = bp[1]; bb[2] = bp[2]; bb[3] = bp[3];
        }
        #pragma unroll
        for (int i = 0; i < 4; ++i)
            #pragma unroll
            for (int j = 0; j < 4; ++j)
                accF[i][j] = fmaf(sv[i][r], tmp2[i][j] + bb[j], accF[i][j]);
    }

    #pragma unroll
    for (int i = 0; i < 4; ++i) {
        int gr = row0 + ty * 4 + i;
        if (gr >= M) continue;
        *(float4*)&Eout[(size_t)gr * 64 + tx * 4] =
            make_float4(accF[i][0], accF[i][1], accF[i][2], accF[i][3]);
    }
}

// ---------------------------------------------------------------------------
// Fused output head: out = sum_s lrelu(Es @ Ws + bs), s = 0..2, one pass.
// ---------------------------------------------------------------------------
__launch_bounds__(256)
__global__ void head_fused(const float* __restrict__ E0, const float* __restrict__ E1,
                           const float* __restrict__ E2,
                           const float* __restrict__ W0, const float* __restrict__ W1,
                           const float* __restrict__ W2,
                           const float* __restrict__ b0, const float* __restrict__ b1,
                           const float* __restrict__ b2,
                           float* __restrict__ out, int M)
{
    __shared__ float As[64][68];
    __shared__ float Bs[64][64];
    const int row0 = blockIdx.x * 64;
    const int t = threadIdx.x;
    const int tx = t & 15, ty = t >> 4;

    const float* Es[3] = {E0, E1, E2};
    const float* Ws[3] = {W0, W1, W2};
    const float* bs[3] = {b0, b1, b2};

    float acc[4][4] = {};

    #pragma unroll
    for (int s = 0; s < 3; ++s) {
        __syncthreads();   // protect As/Bs from previous compute
        {
            int arow = t >> 4, akk = (t & 15) << 2;
            #pragma unroll
            for (int rp = 0; rp < 64; rp += 16) {
                int r = rp + arow, gr = row0 + r;
                float4 v = make_float4(0.f, 0.f, 0.f, 0.f);
                if (gr < M) v = *(const float4*)&Es[s][(size_t)gr * 64 + akk];
                As[akk + 0][r] = v.x; As[akk + 1][r] = v.y;
                As[akk + 2][r] = v.z; As[akk + 3][r] = v.w;
            }
        }
        #pragma unroll
        for (int idx = t; idx < 1024; idx += 256) {
            int k = idx >> 4, c4 = (idx & 15) << 2;
            *(float4*)&Bs[k][c4] = *(const float4*)&Ws[s][(size_t)k * 64 + c4];
        }
        __syncthreads();

        float tmp[4][4] = {};
        #pragma unroll 8
        for (int k = 0; k < 64; ++k) {
            float4 av = *(const float4*)&As[k][ty * 4];
            float4 bv = *(const float4*)&Bs[k][tx * 4];
            float ar[4] = {av.x, av.y, av.z, av.w};
            float br[4] = {bv.x, bv.y, bv.z, bv.w};
            #pragma unroll
            for (int i = 0; i < 4; ++i)
                #pragma unroll
                for (int j = 0; j < 4; ++j)
                    tmp[i][j] = fmaf(ar[i], br[j], tmp[i][j]);
        }
        float bb[4];
        {
            const float* bp = bs[s] + tx * 4;
            bb[0] = bp[0]; bb[1] = bp[1]; bb[2] = bp[2]; bb[3] = bp[3];
        }
        #pragma unroll
        for (int i = 0; i < 4; ++i)
            #pragma unroll
            for (int j = 0; j < 4; ++j)
                acc[i][j] += lrelu(tmp[i][j] + bb[j]);
    }

    #pragma unroll
    for (int i = 0; i < 4; ++i) {
        int gr = row0 + ty * 4 + i;
        if (gr >= M) continue;
        *(float4*)&out[(size_t)gr * 64 + tx * 4] =
            make_float4(acc[i][0], acc[i][1], acc[i][2], acc[i][3]);
    }
}

// ---------------------------------------------------------------------------
// CSR build
// ---------------------------------------------------------------------------
__launch_bounds__(256)
__global__ void deg_slot(const int* __restrict__ dst, int* __restrict__ deg,
                         int* __restrict__ slot)
{
    int e = blockIdx.x * 256 + threadIdx.x;
    if (e < NE) slot[e] = atomicAdd(&deg[dst[e]], 1);
}

__launch_bounds__(256)
__global__ void scan_block_sums(const int* __restrict__ deg, int* __restrict__ bsum)
{
    __shared__ int sh[256];
    int i = blockIdx.x * 256 + threadIdx.x;
    sh[threadIdx.x] = (i < NN) ? deg[i] : 0;
    __syncthreads();
    for (int s = 128; s > 0; s >>= 1) {
        if (threadIdx.x < s) sh[threadIdx.x] += sh[threadIdx.x + s];
        __syncthreads();
    }
    if (threadIdx.x == 0) bsum[blockIdx.x] = sh[0];
}

__launch_bounds__(256)
__global__ void scan_partials(int* __restrict__ bsum, int nb)
{
    __shared__ int sh[256];
    int t = threadIdx.x;
    int v = (t < nb) ? bsum[t] : 0;
    sh[t] = v; __syncthreads();
    for (int off = 1; off < 256; off <<= 1) {
        int x = (t >= off) ? sh[t - off] : 0;
        __syncthreads();
        sh[t] += x;
        __syncthreads();
    }
    if (t < nb) bsum[t] = sh[t] - v;   // exclusive
}

__launch_bounds__(256)
__global__ void scan_final(const int* __restrict__ deg, const int* __restrict__ bsum,
                           int* __restrict__ offs)
{
    __shared__ int sh[256];
    int t = threadIdx.x;
    int i = blockIdx.x * 256 + t;
    int v = (i < NN) ? deg[i] : 0;
    sh[t] = v; __syncthreads();
    for (int off = 1; off < 256; off <<= 1) {
        int x = (t >= off) ? sh[t - off] : 0;
        __syncthreads();
        sh[t] += x;
        __syncthreads();
    }
    int excl = sh[t] - v + bsum[blockIdx.x];
    if (i <= NN) offs[i] = excl;
}

// pure streaming: w[e] = lambda * exp(-etime . beta)
__launch_bounds__(256)
__global__ void w_pass(const float* __restrict__ etime, const float* __restrict__ beta,
                       const float* __restrict__ lambda_p, float* __restrict__ w)
{
    int e = blockIdx.x * 256 + threadIdx.x;
    if (e >= NE) return;
    float b[12];
    #pragma unroll
    for (int j = 0; j < 12; ++j) b[j] = beta[j];
    const float* et = etime + (size_t)e * 12;
    float4 v0 = *(const float4*)(et);
    float4 v1 = *(const float4*)(et + 4);
    float4 v2 = *(const float4*)(et + 8);
    float logit = v0.x*b[0] + v0.y*b[1] + v0.z*b[2] + v0.w*b[3]
                + v1.x*b[4] + v1.y*b[5] + v1.z*b[6] + v1.w*b[7]
                + v2.x*b[8] + v2.y*b[9] + v2.z*b[10] + v2.w*b[11];
    w[e] = lambda_p[0] * expf(-logit);
}

// pure scatter: epack[offs[dst]+slot] = {(r<<16)|src, w}
__launch_bounds__(256)
__global__ void scatter_pass(const int* __restrict__ src, const int* __restrict__ dst,
                             const int* __restrict__ etype, const float* __restrict__ w,
                             const int* __restrict__ slot, const int* __restrict__ offs,
                             uint2* __restrict__ epack)
{
    int e = blockIdx.x * 256 + threadIdx.x;
    if (e >= NE) return;
    int d = dst[e];
    int p = offs[d] + slot[e];
    epack[p] = make_uint2(((unsigned)etype[e] << 16) | (unsigned)src[e],
                          __float_as_uint(w[e]));
}

// S[n,r] = sum of w over node n's CSR range with type r (no atomics)
__launch_bounds__(256)
__global__ void s_sum(const int* __restrict__ offs, const uint2* __restrict__ epack,
                      float* __restrict__ S)
{
    int n = blockIdx.x * 256 + threadIdx.x;
    if (n >= NN) return;
    int s0 = offs[n], s1 = offs[n + 1];
    float acc[RREL] = {};
    for (int p = s0; p < s1; ++p) {
        uint2 a = epack[p];
        int r = (int)(a.x >> 16);
        float we = __uint_as_float(a.y);
        #pragma unroll
        for (int rr = 0; rr < RREL; ++rr)
            acc[rr] += (r == rr) ? we : 0.f;
    }
    #pragma unroll
    for (int rr = 0; rr < RREL; ++rr)
        S[(size_t)n * RREL + rr] = acc[rr];
}

// ---------------------------------------------------------------------------
// gather: one wave per dst node; out[n][lane] += sum_e w*yt[src,r,lane]
// ---------------------------------------------------------------------------
__launch_bounds__(256)
__global__ void gather_nodes(const int* __restrict__ offs, const uint2* __restrict__ epack,
                             const float* __restrict__ yt, float* __restrict__ out)
{
    int wid = (blockIdx.x * 256 + threadIdx.x) >> 6;
    int lane = threadIdx.x & 63;
    if (wid >= NN) return;
    int s0 = offs[wid], s1 = offs[wid + 1];
    size_t orow = ((size_t)wid << 6) + lane;
    float acc = out[orow];          // einit value
    float acc2 = 0.f;
    int p = s0;
    for (; p + 2 <= s1; p += 2) {
        uint2 a = epack[p];
        uint2 bq = epack[p + 1];
        float va = yt[(size_t)(a.x & 0xFFFFu) * 320 + ((a.x >> 16) << 6) + lane];
        float vb = yt[(size_t)(bq.x & 0xFFFFu) * 320 + ((bq.x >> 16) << 6) + lane];
        acc  = fmaf(__uint_as_float(a.y),  va, acc);
        acc2 = fmaf(__uint_as_float(bq.y), vb, acc2);
    }
    if (p < s1) {
        uint2 a = epack[p];
        acc = fmaf(__uint_as_float(a.y),
                   yt[(size_t)(a.x & 0xFFFFu) * 320 + ((a.x >> 16) << 6) + lane], acc);
    }
    out[orow] = acc + acc2;
}

// ---------------------------------------------------------------------------
extern "C" void kernel_launch(void* const* d_in, const int* in_sizes, int n_in,
                              void* d_out, int out_size, void* d_ws, size_t ws_size,
                              hipStream_t stream)
{
    const float* x        = (const float*)d_in[0];
    const int*   eidx     = (const int*)d_in[1];
    const int*   etype    = (const int*)d_in[2];
    const float* etime    = (const float*)d_in[3];
    const float* lambda_p = (const float*)d_in[4];
    const float* beta     = (const float*)d_in[5];
    const float* field_W  = (const float*)d_in[6];
    const float* field_b  = (const float*)d_in[7];
    const float* rel1_W   = (const float*)d_in[8];
    const float* rel1_b   = (const float*)d_in[9];
    const float* rel2_W   = (const float*)d_in[10];
    const float* rel2_b   = (const float*)d_in[11];
    const float* out0_W   = (const float*)d_in[12];
    const float* out0_b   = (const float*)d_in[13];
    const float* out1_W   = (const float*)d_in[14];
    const float* out1_b   = (const float*)d_in[15];
    const float* out2_W   = (const float*)d_in[16];
    const float* out2_b   = (const float*)d_in[17];
    const int* src = eidx;
    const int* dst = eidx + NE;
    float* out = (float*)d_out;

    char* wsb = (char*)d_ws;
    size_t off = 0;
    auto carve = [&](size_t bytes) -> void* {
        void* p = (void*)(wsb + off);
        off += (bytes + 255) & ~(size_t)255;
        return p;
    };
    int*   deg    = (int*)carve((size_t)NN * 4);
    int*   offs   = (int*)carve((size_t)(NN + 1) * 4);
    int*   bsum   = (int*)carve((size_t)SCAN_NB * 4);
    int*   slot   = (int*)carve((size_t)NE * 4);            // 3.2 MB
    float* w_e    = (float*)carve((size_t)NE * 4);          // 3.2 MB
    float* S      = (float*)carve((size_t)NN * RREL * 4);   // 1 MB
    uint2* epack  = (uint2*)carve((size_t)NE * 8);          // 6.4 MB
    float* e0     = (float*)carve((size_t)NN * 64 * 4);     // 12.8 MB
    float* e1     = (float*)carve((size_t)NN * 64 * 4);     // 12.8 MB
    float* e2     = (float*)carve((size_t)NN * 64 * 4);     // 12.8 MB
    float* yt     = (float*)carve((size_t)NN * 320 * 4);    // 64 MB

    const int NT = (NN + 63) / 64;
    dim3 blk(256);
    dim3 g1(NT, 1);
    const int EB = (NE + 255) / 256;
    const int NB = (NN + 255) / 256;
    const int GB = (NN * 64 + 255) / 256;

    // ---- CSR build (layer-shared, atomic-light) ----
    hipMemsetAsync(deg, 0, (size_t)NN * 4, stream);
    deg_slot<<<EB, blk, 0, stream>>>(dst, deg, slot);
    scan_block_sums<<<SCAN_NB, blk, 0, stream>>>(deg, bsum);
    scan_partials<<<1, blk, 0, stream>>>(bsum, SCAN_NB);
    scan_final<<<SCAN_NB, blk, 0, stream>>>(deg, bsum, offs);
    w_pass<<<EB, blk, 0, stream>>>(etime, beta, lambda_p, w_e);
    scatter_pass<<<EB, blk, 0, stream>>>(src, dst, etype, w_e, slot, offs, epack);
    s_sum<<<NB, blk, 0, stream>>>(offs, epack, S);

    // ---- e0 = x @ field_W + field_b ----
    gemm_tile<128><<<g1, blk, 0, stream>>>(x, 128, field_W, field_b, e0, NN);

    // ---- layer 1 ----
    rel_fused<<<g1, blk, 0, stream>>>(e0, rel1_W, rel1_b, S, yt, e1, NN);
    gather_nodes<<<GB, blk, 0, stream>>>(offs, epack, yt, e1);

    // ---- layer 2 ----
    rel_fused<<<g1, blk, 0, stream>>>(e1, rel2_W, rel2_b, S, yt, e2, NN);
    gather_nodes<<<GB, blk, 0, stream>>>(offs, epack, yt, e2);

    // ---- output head (single pass) ----
    head_fused<<<g1, blk, 0, stream>>>(e0, e1, e2, out0_W, out1_W, out2_W,
                                       out0_b, out1_b, out2_b, out, NN);
}

// Round 4
// 376.063 us; speedup vs baseline: 1.6089x; 1.1087x over previous
//
#include <hip/hip_runtime.h>
#include <cstdint>
#include <cstddef>

#define NN 50000
#define NE 800000
#define RREL 5
#define SCAN_NB 196   // ceil(NN/256)

static __device__ __forceinline__ float lrelu(float v) { return v > 0.f ? v : 0.01f * v; }

// ---------------------------------------------------------------------------
// 64x64-tile f32 GEMM (used only for e0 = x @ field_W + field_b, K=128)
// ---------------------------------------------------------------------------
template<int K>
__launch_bounds__(256)
__global__ void gemm_tile(const float* __restrict__ A, int lda,
                          const float* __restrict__ B0,
                          const float* __restrict__ bias,
                          float* __restrict__ C, int M)
{
    __shared__ float As[64][68];   // transposed: As[k][row]
    __shared__ float Bs[64][64];   // Bs[k][col]
    const int row0 = blockIdx.x * 64;
    const int t = threadIdx.x;
    const int tx = t & 15, ty = t >> 4;

    float acc[4][4] = {};

    for (int kc = 0; kc < K; kc += 64) {
        {
            int arow = t >> 4, akk = (t & 15) << 2;
            #pragma unroll
            for (int rp = 0; rp < 64; rp += 16) {
                int r = rp + arow, gr = row0 + r;
                float4 v = make_float4(0.f, 0.f, 0.f, 0.f);
                if (gr < M) v = *(const float4*)&A[(size_t)gr * lda + kc + akk];
                As[akk + 0][r] = v.x; As[akk + 1][r] = v.y;
                As[akk + 2][r] = v.z; As[akk + 3][r] = v.w;
            }
        }
        #pragma unroll
        for (int idx = t; idx < 1024; idx += 256) {
            int k = idx >> 4, c4 = (idx & 15) << 2;
            *(float4*)&Bs[k][c4] = *(const float4*)&B0[(size_t)(kc + k) * 64 + c4];
        }
        __syncthreads();

        #pragma unroll 8
        for (int k = 0; k < 64; ++k) {
            float4 av = *(const float4*)&As[k][ty * 4];
            float4 bv = *(const float4*)&Bs[k][tx * 4];
            float ar[4] = {av.x, av.y, av.z, av.w};
            float br[4] = {bv.x, bv.y, bv.z, bv.w};
            #pragma unroll
            for (int i = 0; i < 4; ++i)
                #pragma unroll
                for (int j = 0; j < 4; ++j)
                    acc[i][j] = fmaf(ar[i], br[j], acc[i][j]);
        }
        __syncthreads();
    }

    float bb[4];
    {
        const float* bp = bias + tx * 4;
        bb[0] = bp[0]; bb[1] = bp[1]; bb[2] = bp[2]; bb[3] = bp[3];
    }
    #pragma unroll
    for (int i = 0; i < 4; ++i) {
        int gr = row0 + ty * 4 + i;
        if (gr >= M) continue;
        *(float4*)&C[(size_t)gr * 64 + tx * 4] =
            make_float4(acc[i][0] + bb[0], acc[i][1] + bb[1],
                        acc[i][2] + bb[2], acc[i][3] + bb[3]);
    }
}

// ---------------------------------------------------------------------------
// ytgemm: grid (ceil(M/128), 10). s = blockIdx.y.
//   s in [0,5):  ybuf[:, s*64 + c]        = A @ Wtop[s]
//   s in [5,10): ybuf[:, 320 + (s-5)*64]  = A @ Wbot[s-5] + b[s-5]
// One barrier per block; 128x64 tile; 8x4 per-thread register tile.
// ---------------------------------------------------------------------------
__launch_bounds__(256)
__global__ void ytgemm(const float* __restrict__ Ain,
                       const float* __restrict__ relW,
                       const float* __restrict__ relb,
                       float* __restrict__ ybuf, int M)
{
    __shared__ float As[64][132];   // As[k][row], rows 0..127 (stride 132: 2-way max)
    __shared__ float Bs[64][64];
    const int s = blockIdx.y;
    const int r = (s >= RREL) ? s - RREL : s;
    const bool bot = (s >= RREL);
    const int row0 = blockIdx.x * 128;
    const int t = threadIdx.x;
    const int tx = t & 15, ty = t >> 4;

    // stage A: thread t -> row t>>1, k-range (t&1)*32 .. +31  (8 float4)
    {
        int arow = t >> 1, gr = row0 + arow;
        int k0 = (t & 1) << 5;
        const float* ap = &Ain[(size_t)gr * 64 + k0];
        #pragma unroll
        for (int q = 0; q < 8; ++q) {
            float4 v = make_float4(0.f, 0.f, 0.f, 0.f);
            if (gr < M) v = *(const float4*)(ap + (q << 2));
            int k = k0 + (q << 2);
            As[k + 0][arow] = v.x; As[k + 1][arow] = v.y;
            As[k + 2][arow] = v.z; As[k + 3][arow] = v.w;
        }
    }
    // stage B (weights, L2-hot)
    {
        const float* W = relW + (size_t)r * 8192 + (bot ? 4096 : 0);
        #pragma unroll
        for (int idx = t; idx < 1024; idx += 256) {
            int k = idx >> 4, c4 = (idx & 15) << 2;
            *(float4*)&Bs[k][c4] = *(const float4*)&W[k * 64 + c4];
        }
    }
    __syncthreads();

    float acc[8][4] = {};
    #pragma unroll 4
    for (int k = 0; k < 64; ++k) {
        float4 a0 = *(const float4*)&As[k][ty * 8];
        float4 a1 = *(const float4*)&As[k][ty * 8 + 4];
        float4 bv = *(const float4*)&Bs[k][tx * 4];
        float ar[8] = {a0.x, a0.y, a0.z, a0.w, a1.x, a1.y, a1.z, a1.w};
        float br[4] = {bv.x, bv.y, bv.z, bv.w};
        #pragma unroll
        for (int i = 0; i < 8; ++i)
            #pragma unroll
            for (int j = 0; j < 4; ++j)
                acc[i][j] = fmaf(ar[i], br[j], acc[i][j]);
    }

    float bb[4] = {0.f, 0.f, 0.f, 0.f};
    if (bot) {
        const float* bp = relb + r * 64 + tx * 4;
        bb[0] = bp[0]; bb[1] = bp[1]; bb[2] = bp[2]; bb[3] = bp[3];
    }
    const size_t ccol = (size_t)s * 64 + tx * 4;   // s>=5 lands at 320 + r*64
    #pragma unroll
    for (int i = 0; i < 8; ++i) {
        int gr = row0 + ty * 8 + i;
        if (gr >= M) continue;
        *(float4*)&ybuf[(size_t)gr * 640 + ccol] =
            make_float4(acc[i][0] + bb[0], acc[i][1] + bb[1],
                        acc[i][2] + bb[2], acc[i][3] + bb[3]);
    }
}

// ---------------------------------------------------------------------------
// Fused output head: out = sum_s lrelu(Es @ Ws + bs)
// ---------------------------------------------------------------------------
__launch_bounds__(256)
__global__ void head_fused(const float* __restrict__ E0, const float* __restrict__ E1,
                           const float* __restrict__ E2,
                           const float* __restrict__ W0, const float* __restrict__ W1,
                           const float* __restrict__ W2,
                           const float* __restrict__ b0, const float* __restrict__ b1,
                           const float* __restrict__ b2,
                           float* __restrict__ out, int M)
{
    __shared__ float As[64][68];
    __shared__ float Bs[64][64];
    const int row0 = blockIdx.x * 64;
    const int t = threadIdx.x;
    const int tx = t & 15, ty = t >> 4;

    const float* Es[3] = {E0, E1, E2};
    const float* Ws[3] = {W0, W1, W2};
    const float* bs[3] = {b0, b1, b2};

    float acc[4][4] = {};

    #pragma unroll
    for (int s = 0; s < 3; ++s) {
        __syncthreads();
        {
            int arow = t >> 4, akk = (t & 15) << 2;
            #pragma unroll
            for (int rp = 0; rp < 64; rp += 16) {
                int r = rp + arow, gr = row0 + r;
                float4 v = make_float4(0.f, 0.f, 0.f, 0.f);
                if (gr < M) v = *(const float4*)&Es[s][(size_t)gr * 64 + akk];
                As[akk + 0][r] = v.x; As[akk + 1][r] = v.y;
                As[akk + 2][r] = v.z; As[akk + 3][r] = v.w;
            }
        }
        #pragma unroll
        for (int idx = t; idx < 1024; idx += 256) {
            int k = idx >> 4, c4 = (idx & 15) << 2;
            *(float4*)&Bs[k][c4] = *(const float4*)&Ws[s][(size_t)k * 64 + c4];
        }
        __syncthreads();

        float tmp[4][4] = {};
        #pragma unroll 8
        for (int k = 0; k < 64; ++k) {
            float4 av = *(const float4*)&As[k][ty * 4];
            float4 bv = *(const float4*)&Bs[k][tx * 4];
            float ar[4] = {av.x, av.y, av.z, av.w};
            float br[4] = {bv.x, bv.y, bv.z, bv.w};
            #pragma unroll
            for (int i = 0; i < 4; ++i)
                #pragma unroll
                for (int j = 0; j < 4; ++j)
                    tmp[i][j] = fmaf(ar[i], br[j], tmp[i][j]);
        }
        float bb[4];
        {
            const float* bp = bs[s] + tx * 4;
            bb[0] = bp[0]; bb[1] = bp[1]; bb[2] = bp[2]; bb[3] = bp[3];
        }
        #pragma unroll
        for (int i = 0; i < 4; ++i)
            #pragma unroll
            for (int j = 0; j < 4; ++j)
                acc[i][j] += lrelu(tmp[i][j] + bb[j]);
    }

    #pragma unroll
    for (int i = 0; i < 4; ++i) {
        int gr = row0 + ty * 4 + i;
        if (gr >= M) continue;
        *(float4*)&out[(size_t)gr * 64 + tx * 4] =
            make_float4(acc[i][0], acc[i][1], acc[i][2], acc[i][3]);
    }
}

// ---------------------------------------------------------------------------
// CSR build
// ---------------------------------------------------------------------------
__launch_bounds__(256)
__global__ void deg_slot(const int* __restrict__ dst, int* __restrict__ deg,
                         int* __restrict__ slot)
{
    int e = blockIdx.x * 256 + threadIdx.x;
    if (e < NE) slot[e] = atomicAdd(&deg[dst[e]], 1);
}

__launch_bounds__(256)
__global__ void scan_block_sums(const int* __restrict__ deg, int* __restrict__ bsum)
{
    __shared__ int sh[256];
    int i = blockIdx.x * 256 + threadIdx.x;
    sh[threadIdx.x] = (i < NN) ? deg[i] : 0;
    __syncthreads();
    for (int s = 128; s > 0; s >>= 1) {
        if (threadIdx.x < s) sh[threadIdx.x] += sh[threadIdx.x + s];
        __syncthreads();
    }
    if (threadIdx.x == 0) bsum[blockIdx.x] = sh[0];
}

__launch_bounds__(256)
__global__ void scan_partials(int* __restrict__ bsum, int nb)
{
    __shared__ int sh[256];
    int t = threadIdx.x;
    int v = (t < nb) ? bsum[t] : 0;
    sh[t] = v; __syncthreads();
    for (int off = 1; off < 256; off <<= 1) {
        int x = (t >= off) ? sh[t - off] : 0;
        __syncthreads();
        sh[t] += x;
        __syncthreads();
    }
    if (t < nb) bsum[t] = sh[t] - v;   // exclusive
}

__launch_bounds__(256)
__global__ void scan_final(const int* __restrict__ deg, const int* __restrict__ bsum,
                           int* __restrict__ offs)
{
    __shared__ int sh[256];
    int t = threadIdx.x;
    int i = blockIdx.x * 256 + t;
    int v = (i < NN) ? deg[i] : 0;
    sh[t] = v; __syncthreads();
    for (int off = 1; off < 256; off <<= 1) {
        int x = (t >= off) ? sh[t - off] : 0;
        __syncthreads();
        sh[t] += x;
        __syncthreads();
    }
    int excl = sh[t] - v + bsum[blockIdx.x];
    if (i <= NN) offs[i] = excl;
}

// pure streaming: w[e] = lambda * exp(-etime . beta)
__launch_bounds__(256)
__global__ void w_pass(const float* __restrict__ etime, const float* __restrict__ beta,
                       const float* __restrict__ lambda_p, float* __restrict__ w)
{
    int e = blockIdx.x * 256 + threadIdx.x;
    if (e >= NE) return;
    float b[12];
    #pragma unroll
    for (int j = 0; j < 12; ++j) b[j] = beta[j];
    const float* et = etime + (size_t)e * 12;
    float4 v0 = *(const float4*)(et);
    float4 v1 = *(const float4*)(et + 4);
    float4 v2 = *(const float4*)(et + 8);
    float logit = v0.x*b[0] + v0.y*b[1] + v0.z*b[2] + v0.w*b[3]
                + v1.x*b[4] + v1.y*b[5] + v1.z*b[6] + v1.w*b[7]
                + v2.x*b[8] + v2.y*b[9] + v2.z*b[10] + v2.w*b[11];
    w[e] = lambda_p[0] * expf(-logit);
}

// pure scatter: epack[offs[dst]+slot] = {(r<<16)|src, w}   (src < 65536 OK: NN=50000)
__launch_bounds__(256)
__global__ void scatter_pass(const int* __restrict__ src, const int* __restrict__ dst,
                             const int* __restrict__ etype, const float* __restrict__ w,
                             const int* __restrict__ slot, const int* __restrict__ offs,
                             uint2* __restrict__ epack)
{
    int e = blockIdx.x * 256 + threadIdx.x;
    if (e >= NE) return;
    int d = dst[e];
    int p = offs[d] + slot[e];
    epack[p] = make_uint2(((unsigned)etype[e] << 16) | (unsigned)src[e],
                          __float_as_uint(w[e]));
}

// S[n,r] = sum of w over node n's CSR range with type r (no atomics)
__launch_bounds__(256)
__global__ void s_sum(const int* __restrict__ offs, const uint2* __restrict__ epack,
                      float* __restrict__ S)
{
    int n = blockIdx.x * 256 + threadIdx.x;
    if (n >= NN) return;
    int s0 = offs[n], s1 = offs[n + 1];
    float acc[RREL] = {};
    for (int p = s0; p < s1; ++p) {
        uint2 a = epack[p];
        int r = (int)(a.x >> 16);
        float we = __uint_as_float(a.y);
        #pragma unroll
        for (int rr = 0; rr < RREL; ++rr)
            acc[rr] += (r == rr) ? we : 0.f;
    }
    #pragma unroll
    for (int rr = 0; rr < RREL; ++rr)
        S[(size_t)n * RREL + rr] = acc[rr];
}

// ---------------------------------------------------------------------------
// gather: one wave per dst node.
// out[n][lane] = sum_r S[n,r]*ybuf[n][320+r*64+lane]      (einit, inline)
//              + sum_edges w * ybuf[src][r*64+lane]        (messages)
// ---------------------------------------------------------------------------
__launch_bounds__(256)
__global__ void gather_nodes(const int* __restrict__ offs, const uint2* __restrict__ epack,
                             const float* __restrict__ S, const float* __restrict__ ybuf,
                             float* __restrict__ out)
{
    int wid = (blockIdx.x * 256 + threadIdx.x) >> 6;
    int lane = threadIdx.x & 63;
    if (wid >= NN) return;

    // einit part (own row: coalesced; S broadcast)
    const float* yrow = ybuf + (size_t)wid * 640 + 320 + lane;
    const float* sp = S + (size_t)wid * RREL;
    float acc = 0.f, acc2 = 0.f;
    #pragma unroll
    for (int r = 0; r < RREL; ++r)
        acc = fmaf(sp[r], yrow[r << 6], acc);

    // edge part
    int s0 = offs[wid], s1 = offs[wid + 1];
    int p = s0;
    for (; p + 2 <= s1; p += 2) {
        uint2 a = epack[p];
        uint2 bq = epack[p + 1];
        float va = ybuf[(size_t)(a.x & 0xFFFFu) * 640 + ((a.x >> 16) << 6) + lane];
        float vb = ybuf[(size_t)(bq.x & 0xFFFFu) * 640 + ((bq.x >> 16) << 6) + lane];
        acc  = fmaf(__uint_as_float(a.y),  va, acc);
        acc2 = fmaf(__uint_as_float(bq.y), vb, acc2);
    }
    if (p < s1) {
        uint2 a = epack[p];
        acc = fmaf(__uint_as_float(a.y),
                   ybuf[(size_t)(a.x & 0xFFFFu) * 640 + ((a.x >> 16) << 6) + lane], acc);
    }
    out[((size_t)wid << 6) + lane] = acc + acc2;
}

// ---------------------------------------------------------------------------
extern "C" void kernel_launch(void* const* d_in, const int* in_sizes, int n_in,
                              void* d_out, int out_size, void* d_ws, size_t ws_size,
                              hipStream_t stream)
{
    const float* x        = (const float*)d_in[0];
    const int*   eidx     = (const int*)d_in[1];
    const int*   etype    = (const int*)d_in[2];
    const float* etime    = (const float*)d_in[3];
    const float* lambda_p = (const float*)d_in[4];
    const float* beta     = (const float*)d_in[5];
    const float* field_W  = (const float*)d_in[6];
    const float* field_b  = (const float*)d_in[7];
    const float* rel1_W   = (const float*)d_in[8];
    const float* rel1_b   = (const float*)d_in[9];
    const float* rel2_W   = (const float*)d_in[10];
    const float* rel2_b   = (const float*)d_in[11];
    const float* out0_W   = (const float*)d_in[12];
    const float* out0_b   = (const float*)d_in[13];
    const float* out1_W   = (const float*)d_in[14];
    const float* out1_b   = (const float*)d_in[15];
    const float* out2_W   = (const float*)d_in[16];
    const float* out2_b   = (const float*)d_in[17];
    const int* src = eidx;
    const int* dst = eidx + NE;
    float* out = (float*)d_out;

    char* wsb = (char*)d_ws;
    size_t off = 0;
    auto carve = [&](size_t bytes) -> void* {
        void* p = (void*)(wsb + off);
        off += (bytes + 255) & ~(size_t)255;
        return p;
    };
    int*   deg    = (int*)carve((size_t)NN * 4);
    int*   offs   = (int*)carve((size_t)(NN + 1) * 4);
    int*   bsum   = (int*)carve((size_t)SCAN_NB * 4);
    int*   slot   = (int*)carve((size_t)NE * 4);            // 3.2 MB
    float* w_e    = (float*)carve((size_t)NE * 4);          // 3.2 MB
    float* S      = (float*)carve((size_t)NN * RREL * 4);   // 1 MB
    uint2* epack  = (uint2*)carve((size_t)NE * 8);          // 6.4 MB
    float* e0     = (float*)carve((size_t)NN * 64 * 4);     // 12.8 MB
    float* e1     = (float*)carve((size_t)NN * 64 * 4);     // 12.8 MB
    float* e2     = (float*)carve((size_t)NN * 64 * 4);     // 12.8 MB
    float* ybuf   = (float*)carve((size_t)NN * 640 * 4);    // 128 MB

    dim3 blk(256);
    const int NT64  = (NN + 63) / 64;     // 782
    const int NT128 = (NN + 127) / 128;   // 391
    dim3 gY(NT128, 2 * RREL);
    const int EB = (NE + 255) / 256;
    const int NB = (NN + 255) / 256;
    const int GB = (NN * 64 + 255) / 256;

    // ---- CSR build (layer-shared) ----
    hipMemsetAsync(deg, 0, (size_t)NN * 4, stream);
    deg_slot<<<EB, blk, 0, stream>>>(dst, deg, slot);
    scan_block_sums<<<SCAN_NB, blk, 0, stream>>>(deg, bsum);
    scan_partials<<<1, blk, 0, stream>>>(bsum, SCAN_NB);
    scan_final<<<SCAN_NB, blk, 0, stream>>>(deg, bsum, offs);
    w_pass<<<EB, blk, 0, stream>>>(etime, beta, lambda_p, w_e);
    scatter_pass<<<EB, blk, 0, stream>>>(src, dst, etype, w_e, slot, offs, epack);
    s_sum<<<NB, blk, 0, stream>>>(offs, epack, S);

    // ---- e0 = x @ field_W + field_b ----
    gemm_tile<128><<<dim3(NT64), blk, 0, stream>>>(x, 128, field_W, field_b, e0, NN);

    // ---- layer 1 ----
    ytgemm<<<gY, blk, 0, stream>>>(e0, rel1_W, rel1_b, ybuf, NN);
    gather_nodes<<<GB, blk, 0, stream>>>(offs, epack, S, ybuf, e1);

    // ---- layer 2 ----
    ytgemm<<<gY, blk, 0, stream>>>(e1, rel2_W, rel2_b, ybuf, NN);
    gather_nodes<<<GB, blk, 0, stream>>>(offs, epack, S, ybuf, e2);

    // ---- output head (single pass) ----
    head_fused<<<dim3(NT64), blk, 0, stream>>>(e0, e1, e2, out0_W, out1_W, out2_W,
                                               out0_b, out1_b, out2_b, out, NN);
}

// Round 5
// 369.828 us; speedup vs baseline: 1.6360x; 1.0169x over previous
//
#include <hip/hip_runtime.h>
#include <cstdint>
#include <cstddef>

#define NN 50000
#define NE 800000
#define RREL 5
#define SCAN_NB 196   // ceil(NN/256)

static __device__ __forceinline__ float lrelu(float v) { return v > 0.f ? v : 0.01f * v; }

// ---------------------------------------------------------------------------
// 64x64-tile f32 GEMM (used only for e0 = x @ field_W + field_b, K=128)
// ---------------------------------------------------------------------------
template<int K>
__launch_bounds__(256)
__global__ void gemm_tile(const float* __restrict__ A, int lda,
                          const float* __restrict__ B0,
                          const float* __restrict__ bias,
                          float* __restrict__ C, int M)
{
    __shared__ float As[64][68];   // transposed: As[k][row]
    __shared__ float Bs[64][64];   // Bs[k][col]
    const int row0 = blockIdx.x * 64;
    const int t = threadIdx.x;
    const int tx = t & 15, ty = t >> 4;

    float acc[4][4] = {};

    for (int kc = 0; kc < K; kc += 64) {
        {
            int arow = t >> 4, akk = (t & 15) << 2;
            #pragma unroll
            for (int rp = 0; rp < 64; rp += 16) {
                int r = rp + arow, gr = row0 + r;
                float4 v = make_float4(0.f, 0.f, 0.f, 0.f);
                if (gr < M) v = *(const float4*)&A[(size_t)gr * lda + kc + akk];
                As[akk + 0][r] = v.x; As[akk + 1][r] = v.y;
                As[akk + 2][r] = v.z; As[akk + 3][r] = v.w;
            }
        }
        #pragma unroll
        for (int idx = t; idx < 1024; idx += 256) {
            int k = idx >> 4, c4 = (idx & 15) << 2;
            *(float4*)&Bs[k][c4] = *(const float4*)&B0[(size_t)(kc + k) * 64 + c4];
        }
        __syncthreads();

        #pragma unroll 8
        for (int k = 0; k < 64; ++k) {
            float4 av = *(const float4*)&As[k][ty * 4];
            float4 bv = *(const float4*)&Bs[k][tx * 4];
            float ar[4] = {av.x, av.y, av.z, av.w};
            float br[4] = {bv.x, bv.y, bv.z, bv.w};
            #pragma unroll
            for (int i = 0; i < 4; ++i)
                #pragma unroll
                for (int j = 0; j < 4; ++j)
                    acc[i][j] = fmaf(ar[i], br[j], acc[i][j]);
        }
        __syncthreads();
    }

    float bb[4];
    {
        const float* bp = bias + tx * 4;
        bb[0] = bp[0]; bb[1] = bp[1]; bb[2] = bp[2]; bb[3] = bp[3];
    }
    #pragma unroll
    for (int i = 0; i < 4; ++i) {
        int gr = row0 + ty * 4 + i;
        if (gr >= M) continue;
        *(float4*)&C[(size_t)gr * 64 + tx * 4] =
            make_float4(acc[i][0] + bb[0], acc[i][1] + bb[1],
                        acc[i][2] + bb[2], acc[i][3] + bb[3]);
    }
}

// ---------------------------------------------------------------------------
// zgather: one wave per dst node.
//   Z[n][r*64+lane] = sum_{e->n, type r} w_e * e_prev[src_e][lane]
//   S[n][r]         = sum_{e->n, type r} w_e        (lane 0 writes)
// Random reads hit e_prev (12.8 MB, cache-friendly); all writes dense.
// ---------------------------------------------------------------------------
__launch_bounds__(256)
__global__ void zgather(const int* __restrict__ offs, const uint2* __restrict__ epack,
                        const float* __restrict__ Eprev,
                        float* __restrict__ Z, float* __restrict__ S)
{
    int wid = (blockIdx.x * 256 + threadIdx.x) >> 6;
    int lane = threadIdx.x & 63;
    if (wid >= NN) return;
    int s0 = offs[wid], s1 = offs[wid + 1];

    float a0 = 0.f, a1 = 0.f, a2 = 0.f, a3 = 0.f, a4 = 0.f;
    float s0v = 0.f, s1v = 0.f, s2v = 0.f, s3v = 0.f, s4v = 0.f;

    int p = s0;
    for (; p + 4 <= s1; p += 4) {
        uint2 q0 = epack[p + 0], q1 = epack[p + 1];
        uint2 q2 = epack[p + 2], q3 = epack[p + 3];
        float v0 = Eprev[(size_t)(q0.x & 0xFFFFu) * 64 + lane];
        float v1 = Eprev[(size_t)(q1.x & 0xFFFFu) * 64 + lane];
        float v2 = Eprev[(size_t)(q2.x & 0xFFFFu) * 64 + lane];
        float v3 = Eprev[(size_t)(q3.x & 0xFFFFu) * 64 + lane];
        #pragma unroll
        for (int ii = 0; ii < 4; ++ii) {
            uint2 q = (ii == 0) ? q0 : (ii == 1) ? q1 : (ii == 2) ? q2 : q3;
            float v = (ii == 0) ? v0 : (ii == 1) ? v1 : (ii == 2) ? v2 : v3;
            unsigned r = q.x >> 16;
            float w = __uint_as_float(q.y);
            float w0 = (r == 0) ? w : 0.f, w1 = (r == 1) ? w : 0.f;
            float w2 = (r == 2) ? w : 0.f, w3 = (r == 3) ? w : 0.f;
            float w4 = (r == 4) ? w : 0.f;
            a0 = fmaf(w0, v, a0); a1 = fmaf(w1, v, a1); a2 = fmaf(w2, v, a2);
            a3 = fmaf(w3, v, a3); a4 = fmaf(w4, v, a4);
            s0v += w0; s1v += w1; s2v += w2; s3v += w3; s4v += w4;
        }
    }
    for (; p < s1; ++p) {
        uint2 q = epack[p];
        float v = Eprev[(size_t)(q.x & 0xFFFFu) * 64 + lane];
        unsigned r = q.x >> 16;
        float w = __uint_as_float(q.y);
        float w0 = (r == 0) ? w : 0.f, w1 = (r == 1) ? w : 0.f;
        float w2 = (r == 2) ? w : 0.f, w3 = (r == 3) ? w : 0.f;
        float w4 = (r == 4) ? w : 0.f;
        a0 = fmaf(w0, v, a0); a1 = fmaf(w1, v, a1); a2 = fmaf(w2, v, a2);
        a3 = fmaf(w3, v, a3); a4 = fmaf(w4, v, a4);
        s0v += w0; s1v += w1; s2v += w2; s3v += w3; s4v += w4;
    }

    float* zr = Z + (size_t)wid * 320 + lane;
    zr[0]   = a0; zr[64]  = a1; zr[128] = a2; zr[192] = a3; zr[256] = a4;
    if (lane == 0) {
        float* sp = S + (size_t)wid * RREL;
        sp[0] = s0v; sp[1] = s1v; sp[2] = s2v; sp[3] = s3v; sp[4] = s4v;
    }
}

// ---------------------------------------------------------------------------
// zgemm: e_next = sum_r Z_r @ Wtop_r + sum_r S_r * (e_prev @ Wbot_r + b_r)
// 10 phases (5 Z-chunks + 5 bot over a once-staged e_prev tile).
// Next phase's A/B are prefetched into registers during current compute, so
// barriers only cover LDS writes (not global latency).
// relW layout [R][128][64]: Wtop_r at r*8192, Wbot_r at r*8192+4096.
// ---------------------------------------------------------------------------
__launch_bounds__(256)
__global__ void zgemm(const float* __restrict__ Z,
                      const float* __restrict__ Eprev,
                      const float* __restrict__ relW,
                      const float* __restrict__ relb,
                      const float* __restrict__ S,
                      float* __restrict__ Enext, int M)
{
    __shared__ float As[64][68];   // As[k][row] (transposed), 16B-aligned rows
    __shared__ float Bs[64][64];
    const int row0 = blockIdx.x * 64;
    const int t = threadIdx.x;
    const int tx = t & 15, ty = t >> 4;

    const int arow = t >> 2;         // 0..63 (4 threads per row)
    const int ak0  = (t & 3) << 4;   // 0,16,32,48

    float4 Areg[4], Breg[4];
    // prologue: phase 0 (A = Z chunk 0, B = Wtop_0)
    {
        int gr = row0 + arow;
        const float* ap = Z + (size_t)gr * 320 + ak0;
        #pragma unroll
        for (int q = 0; q < 4; ++q)
            Areg[q] = (gr < M) ? *(const float4*)(ap + (q << 2))
                               : make_float4(0.f, 0.f, 0.f, 0.f);
        #pragma unroll
        for (int j = 0; j < 4; ++j)
            Breg[j] = *(const float4*)&relW[(size_t)(t + 256 * j) * 4];
    }

    float sv[4][RREL];
    #pragma unroll
    for (int i = 0; i < 4; ++i) {
        int gr = row0 + ty * 4 + i;
        #pragma unroll
        for (int r = 0; r < RREL; ++r)
            sv[i][r] = (gr < M) ? S[(size_t)gr * RREL + r] : 0.f;
    }

    float acc[4][4] = {};

    #pragma unroll
    for (int p = 0; p < 10; ++p) {
        if (p > 0) __syncthreads();          // done reading previous phase
        if (p <= 5) {                        // phases 6..9 reuse e_prev tile
            #pragma unroll
            for (int q = 0; q < 4; ++q) {
                int k = ak0 + (q << 2);
                As[k + 0][arow] = Areg[q].x; As[k + 1][arow] = Areg[q].y;
                As[k + 2][arow] = Areg[q].z; As[k + 3][arow] = Areg[q].w;
            }
        }
        #pragma unroll
        for (int j = 0; j < 4; ++j)
            *(float4*)&Bs[0][(size_t)(t + 256 * j) * 4] = Breg[j];
        __syncthreads();

        // prefetch phase p+1 into registers (overlaps compute below)
        if (p < 9) {
            if (p + 1 <= 5) {
                int gr = row0 + arow;
                const float* ap = (p + 1 < 5)
                    ? Z + (size_t)gr * 320 + (p + 1) * 64 + ak0
                    : Eprev + (size_t)gr * 64 + ak0;
                #pragma unroll
                for (int q = 0; q < 4; ++q)
                    Areg[q] = (gr < M) ? *(const float4*)(ap + (q << 2))
                                       : make_float4(0.f, 0.f, 0.f, 0.f);
            }
            const float* bp = relW + ((p + 1 < 5) ? (size_t)(p + 1) * 8192
                                                  : (size_t)(p - 4) * 8192 + 4096);
            #pragma unroll
            for (int j = 0; j < 4; ++j)
                Breg[j] = *(const float4*)&bp[(size_t)(t + 256 * j) * 4];
        }

        if (p < 5) {
            #pragma unroll 4
            for (int k = 0; k < 64; ++k) {
                float4 av = *(const float4*)&As[k][ty * 4];
                float4 bv = *(const float4*)&Bs[k][tx * 4];
                float ar[4] = {av.x, av.y, av.z, av.w};
                float br[4] = {bv.x, bv.y, bv.z, bv.w};
                #pragma unroll
                for (int i = 0; i < 4; ++i)
                    #pragma unroll
                    for (int j = 0; j < 4; ++j)
                        acc[i][j] = fmaf(ar[i], br[j], acc[i][j]);
            }
        } else {
            float tmp[4][4] = {};
            #pragma unroll 4
            for (int k = 0; k < 64; ++k) {
                float4 av = *(const float4*)&As[k][ty * 4];
                float4 bv = *(const float4*)&Bs[k][tx * 4];
                float ar[4] = {av.x, av.y, av.z, av.w};
                float br[4] = {bv.x, bv.y, bv.z, bv.w};
                #pragma unroll
                for (int i = 0; i < 4; ++i)
                    #pragma unroll
                    for (int j = 0; j < 4; ++j)
                        tmp[i][j] = fmaf(ar[i], br[j], tmp[i][j]);
            }
            const int r = p - 5;
            float4 bq = *(const float4*)&relb[r * 64 + tx * 4];
            float bbr[4] = {bq.x, bq.y, bq.z, bq.w};
            #pragma unroll
            for (int i = 0; i < 4; ++i)
                #pragma unroll
                for (int j = 0; j < 4; ++j)
                    acc[i][j] = fmaf(sv[i][r], tmp[i][j] + bbr[j], acc[i][j]);
        }
    }

    #pragma unroll
    for (int i = 0; i < 4; ++i) {
        int gr = row0 + ty * 4 + i;
        if (gr >= M) continue;
        *(float4*)&Enext[(size_t)gr * 64 + tx * 4] =
            make_float4(acc[i][0], acc[i][1], acc[i][2], acc[i][3]);
    }
}

// ---------------------------------------------------------------------------
// Fused output head: out = sum_s lrelu(Es @ Ws + bs)
// ---------------------------------------------------------------------------
__launch_bounds__(256)
__global__ void head_fused(const float* __restrict__ E0, const float* __restrict__ E1,
                           const float* __restrict__ E2,
                           const float* __restrict__ W0, const float* __restrict__ W1,
                           const float* __restrict__ W2,
                           const float* __restrict__ b0, const float* __restrict__ b1,
                           const float* __restrict__ b2,
                           float* __restrict__ out, int M)
{
    __shared__ float As[64][68];
    __shared__ float Bs[64][64];
    const int row0 = blockIdx.x * 64;
    const int t = threadIdx.x;
    const int tx = t & 15, ty = t >> 4;

    const float* Es[3] = {E0, E1, E2};
    const float* Ws[3] = {W0, W1, W2};
    const float* bs[3] = {b0, b1, b2};

    float acc[4][4] = {};

    #pragma unroll
    for (int s = 0; s < 3; ++s) {
        __syncthreads();
        {
            int arow = t >> 4, akk = (t & 15) << 2;
            #pragma unroll
            for (int rp = 0; rp < 64; rp += 16) {
                int r = rp + arow, gr = row0 + r;
                float4 v = make_float4(0.f, 0.f, 0.f, 0.f);
                if (gr < M) v = *(const float4*)&Es[s][(size_t)gr * 64 + akk];
                As[akk + 0][r] = v.x; As[akk + 1][r] = v.y;
                As[akk + 2][r] = v.z; As[akk + 3][r] = v.w;
            }
        }
        #pragma unroll
        for (int idx = t; idx < 1024; idx += 256) {
            int k = idx >> 4, c4 = (idx & 15) << 2;
            *(float4*)&Bs[k][c4] = *(const float4*)&Ws[s][(size_t)k * 64 + c4];
        }
        __syncthreads();

        float tmp[4][4] = {};
        #pragma unroll 8
        for (int k = 0; k < 64; ++k) {
            float4 av = *(const float4*)&As[k][ty * 4];
            float4 bv = *(const float4*)&Bs[k][tx * 4];
            float ar[4] = {av.x, av.y, av.z, av.w};
            float br[4] = {bv.x, bv.y, bv.z, bv.w};
            #pragma unroll
            for (int i = 0; i < 4; ++i)
                #pragma unroll
                for (int j = 0; j < 4; ++j)
                    tmp[i][j] = fmaf(ar[i], br[j], tmp[i][j]);
        }
        float bb[4];
        {
            const float* bp = bs[s] + tx * 4;
            bb[0] = bp[0]; bb[1] = bp[1]; bb[2] = bp[2]; bb[3] = bp[3];
        }
        #pragma unroll
        for (int i = 0; i < 4; ++i)
            #pragma unroll
            for (int j = 0; j < 4; ++j)
                acc[i][j] += lrelu(tmp[i][j] + bb[j]);
    }

    #pragma unroll
    for (int i = 0; i < 4; ++i) {
        int gr = row0 + ty * 4 + i;
        if (gr >= M) continue;
        *(float4*)&out[(size_t)gr * 64 + tx * 4] =
            make_float4(acc[i][0], acc[i][1], acc[i][2], acc[i][3]);
    }
}

// ---------------------------------------------------------------------------
// CSR build
// ---------------------------------------------------------------------------
__launch_bounds__(256)
__global__ void deg_slot(const int* __restrict__ dst, int* __restrict__ deg,
                         int* __restrict__ slot)
{
    int e = blockIdx.x * 256 + threadIdx.x;
    if (e < NE) slot[e] = atomicAdd(&deg[dst[e]], 1);
}

__launch_bounds__(256)
__global__ void scan_block_sums(const int* __restrict__ deg, int* __restrict__ bsum)
{
    __shared__ int sh[256];
    int i = blockIdx.x * 256 + threadIdx.x;
    sh[threadIdx.x] = (i < NN) ? deg[i] : 0;
    __syncthreads();
    for (int s = 128; s > 0; s >>= 1) {
        if (threadIdx.x < s) sh[threadIdx.x] += sh[threadIdx.x + s];
        __syncthreads();
    }
    if (threadIdx.x == 0) bsum[blockIdx.x] = sh[0];
}

__launch_bounds__(256)
__global__ void scan_partials(int* __restrict__ bsum, int nb)
{
    __shared__ int sh[256];
    int t = threadIdx.x;
    int v = (t < nb) ? bsum[t] : 0;
    sh[t] = v; __syncthreads();
    for (int off = 1; off < 256; off <<= 1) {
        int x = (t >= off) ? sh[t - off] : 0;
        __syncthreads();
        sh[t] += x;
        __syncthreads();
    }
    if (t < nb) bsum[t] = sh[t] - v;   // exclusive
}

__launch_bounds__(256)
__global__ void scan_final(const int* __restrict__ deg, const int* __restrict__ bsum,
                           int* __restrict__ offs)
{
    __shared__ int sh[256];
    int t = threadIdx.x;
    int i = blockIdx.x * 256 + t;
    int v = (i < NN) ? deg[i] : 0;
    sh[t] = v; __syncthreads();
    for (int off = 1; off < 256; off <<= 1) {
        int x = (t >= off) ? sh[t - off] : 0;
        __syncthreads();
        sh[t] += x;
        __syncthreads();
    }
    int excl = sh[t] - v + bsum[blockIdx.x];
    if (i <= NN) offs[i] = excl;
}

// pure streaming: w[e] = lambda * exp(-etime . beta)
__launch_bounds__(256)
__global__ void w_pass(const float* __restrict__ etime, const float* __restrict__ beta,
                       const float* __restrict__ lambda_p, float* __restrict__ w)
{
    int e = blockIdx.x * 256 + threadIdx.x;
    if (e >= NE) return;
    float b[12];
    #pragma unroll
    for (int j = 0; j < 12; ++j) b[j] = beta[j];
    const float* et = etime + (size_t)e * 12;
    float4 v0 = *(const float4*)(et);
    float4 v1 = *(const float4*)(et + 4);
    float4 v2 = *(const float4*)(et + 8);
    float logit = v0.x*b[0] + v0.y*b[1] + v0.z*b[2] + v0.w*b[3]
                + v1.x*b[4] + v1.y*b[5] + v1.z*b[6] + v1.w*b[7]
                + v2.x*b[8] + v2.y*b[9] + v2.z*b[10] + v2.w*b[11];
    w[e] = lambda_p[0] * expf(-logit);
}

// pure scatter: epack[offs[dst]+slot] = {(r<<16)|src, w}   (src < 65536 OK)
__launch_bounds__(256)
__global__ void scatter_pass(const int* __restrict__ src, const int* __restrict__ dst,
                             const int* __restrict__ etype, const float* __restrict__ w,
                             const int* __restrict__ slot, const int* __restrict__ offs,
                             uint2* __restrict__ epack)
{
    int e = blockIdx.x * 256 + threadIdx.x;
    if (e >= NE) return;
    int d = dst[e];
    int p = offs[d] + slot[e];
    epack[p] = make_uint2(((unsigned)etype[e] << 16) | (unsigned)src[e],
                          __float_as_uint(w[e]));
}

// ---------------------------------------------------------------------------
extern "C" void kernel_launch(void* const* d_in, const int* in_sizes, int n_in,
                              void* d_out, int out_size, void* d_ws, size_t ws_size,
                              hipStream_t stream)
{
    const float* x        = (const float*)d_in[0];
    const int*   eidx     = (const int*)d_in[1];
    const int*   etype    = (const int*)d_in[2];
    const float* etime    = (const float*)d_in[3];
    const float* lambda_p = (const float*)d_in[4];
    const float* beta     = (const float*)d_in[5];
    const float* field_W  = (const float*)d_in[6];
    const float* field_b  = (const float*)d_in[7];
    const float* rel1_W   = (const float*)d_in[8];
    const float* rel1_b   = (const float*)d_in[9];
    const float* rel2_W   = (const float*)d_in[10];
    const float* rel2_b   = (const float*)d_in[11];
    const float* out0_W   = (const float*)d_in[12];
    const float* out0_b   = (const float*)d_in[13];
    const float* out1_W   = (const float*)d_in[14];
    const float* out1_b   = (const float*)d_in[15];
    const float* out2_W   = (const float*)d_in[16];
    const float* out2_b   = (const float*)d_in[17];
    const int* src = eidx;
    const int* dst = eidx + NE;
    float* out = (float*)d_out;

    char* wsb = (char*)d_ws;
    size_t off = 0;
    auto carve = [&](size_t bytes) -> void* {
        void* p = (void*)(wsb + off);
        off += (bytes + 255) & ~(size_t)255;
        return p;
    };
    int*   deg    = (int*)carve((size_t)NN * 4);
    int*   offs   = (int*)carve((size_t)(NN + 1) * 4);
    int*   bsum   = (int*)carve((size_t)SCAN_NB * 4);
    int*   slot   = (int*)carve((size_t)NE * 4);            // 3.2 MB
    float* w_e    = (float*)carve((size_t)NE * 4);          // 3.2 MB
    float* S      = (float*)carve((size_t)NN * RREL * 4);   // 1 MB
    uint2* epack  = (uint2*)carve((size_t)NE * 8);          // 6.4 MB
    float* e0     = (float*)carve((size_t)NN * 64 * 4);     // 12.8 MB
    float* e1     = (float*)carve((size_t)NN * 64 * 4);     // 12.8 MB
    float* e2     = (float*)carve((size_t)NN * 64 * 4);     // 12.8 MB
    float* Zb     = (float*)carve((size_t)NN * 320 * 4);    // 64 MB

    dim3 blk(256);
    const int NT64 = (NN + 63) / 64;     // 782
    const int EB = (NE + 255) / 256;
    const int GB = (NN * 64 + 255) / 256;   // one wave per node

    // ---- CSR build (layer-shared) ----
    hipMemsetAsync(deg, 0, (size_t)NN * 4, stream);
    deg_slot<<<EB, blk, 0, stream>>>(dst, deg, slot);
    scan_block_sums<<<SCAN_NB, blk, 0, stream>>>(deg, bsum);
    scan_partials<<<1, blk, 0, stream>>>(bsum, SCAN_NB);
    scan_final<<<SCAN_NB, blk, 0, stream>>>(deg, bsum, offs);
    w_pass<<<EB, blk, 0, stream>>>(etime, beta, lambda_p, w_e);
    scatter_pass<<<EB, blk, 0, stream>>>(src, dst, etype, w_e, slot, offs, epack);

    // ---- e0 = x @ field_W + field_b ----
    gemm_tile<128><<<dim3(NT64), blk, 0, stream>>>(x, 128, field_W, field_b, e0, NN);

    // ---- layer 1 ----
    zgather<<<GB, blk, 0, stream>>>(offs, epack, e0, Zb, S);
    zgemm<<<dim3(NT64), blk, 0, stream>>>(Zb, e0, rel1_W, rel1_b, S, e1, NN);

    // ---- layer 2 ----
    zgather<<<GB, blk, 0, stream>>>(offs, epack, e1, Zb, S);
    zgemm<<<dim3(NT64), blk, 0, stream>>>(Zb, e1, rel2_W, rel2_b, S, e2, NN);

    // ---- output head (single pass) ----
    head_fused<<<dim3(NT64), blk, 0, stream>>>(e0, e1, e2, out0_W, out1_W, out2_W,
                                               out0_b, out1_b, out2_b, out, NN);
}